// Round 16
// baseline (1771.804 us; speedup 1.0000x reference)
//
#include <hip/hip_runtime.h>
#include <cstdint>
#include <cstddef>

#define D_MODEL 512
#define NHEAD   8
#define DH      64
#define B_SZ    4
#define L_SEQ   2048
#define U_TOP   38          // int(5*ln(2048)) = 38
#define QPB     16          // queries per block (2 per wave, 8 waves)
#define KT      128         // key tile staged in LDS
#define TILE_DW (KT * DH)   // 8192 dwords per tile

// monotone float<->uint mapping (order-preserving, exact)
__device__ __forceinline__ unsigned mapmono(float f) {
    unsigned u = __float_as_uint(f);
    return (u & 0x80000000u) ? ~u : (u | 0x80000000u);
}

// ---------------- fp32 GEMM: C(8192x512) = A @ W + b ----------------
// Accurate tiled version for V and the output projection (order-insensitive).
// MODE 0: C row-major (b,l,dm)   MODE 1: scatter to (b,h,l,d)
template<int MODE>
__global__ __launch_bounds__(256)
void gemm512(const float* __restrict__ A, const float* __restrict__ W,
             const float* __restrict__ bias, float* __restrict__ C)
{
    __shared__ float As[16][68];
    __shared__ float Bs[16][68];
    const int tid  = threadIdx.x;
    const int row0 = blockIdx.x * 64;
    const int col0 = blockIdx.y * 64;
    const int ty = tid >> 4, tx = tid & 15;
    float acc[4][4] = {};

    for (int kt = 0; kt < D_MODEL; kt += 16) {
        {
            const int m = tid >> 2, k = (tid & 3) << 2;
            const float4 a = *reinterpret_cast<const float4*>(
                &A[(size_t)(row0 + m) * D_MODEL + kt + k]);
            As[k + 0][m] = a.x; As[k + 1][m] = a.y;
            As[k + 2][m] = a.z; As[k + 3][m] = a.w;
        }
        {
            const int k = tid >> 4, n = (tid & 15) << 2;
            *reinterpret_cast<float4*>(&Bs[k][n]) =
                *reinterpret_cast<const float4*>(
                    &W[(size_t)(kt + k) * D_MODEL + col0 + n]);
        }
        __syncthreads();
        #pragma unroll
        for (int kk = 0; kk < 16; ++kk) {
            const float4 a4 = *reinterpret_cast<const float4*>(&As[kk][ty << 2]);
            const float4 b4 = *reinterpret_cast<const float4*>(&Bs[kk][tx << 2]);
            const float av[4] = {a4.x, a4.y, a4.z, a4.w};
            const float bv[4] = {b4.x, b4.y, b4.z, b4.w};
            #pragma unroll
            for (int i = 0; i < 4; ++i)
                #pragma unroll
                for (int j = 0; j < 4; ++j)
                    acc[i][j] += av[i] * bv[j];
        }
        __syncthreads();
    }

    #pragma unroll
    for (int i = 0; i < 4; ++i) {
        const int r = row0 + (ty << 2) + i;
        const int cb = col0 + (tx << 2);
        float4 v;
        v.x = acc[i][0] + bias[cb + 0];
        v.y = acc[i][1] + bias[cb + 1];
        v.z = acc[i][2] + bias[cb + 2];
        v.w = acc[i][3] + bias[cb + 3];
        if (MODE == 0) {
            *reinterpret_cast<float4*>(&C[(size_t)r * D_MODEL + cb]) = v;
        } else {
            const int b = r >> 11, l = r & (L_SEQ - 1);
            const int h = cb >> 6, d = cb & 63;
            *reinterpret_cast<float4*>(
                &C[(size_t)((b * NHEAD + h) * L_SEQ + l) * DH + d]) = v;
        }
    }
}

// ----- np-replica GEMM for Q,K: SINGLE K-panel sequential FMA chain -----
// (LOCKED arithmetic — passed round 9. Per C element: ONE fp32 accumulator,
// FMA over k=0..511 ascending, then one fp32 bias add.)
__global__ __launch_bounds__(256)
void chain_gemm_qk(const float* __restrict__ x, const float* __restrict__ W,
                   const float* __restrict__ bias, float* __restrict__ Out)
{
    const int tid  = threadIdx.x;
    const int col  = blockIdx.y * 256 + tid;        // 0..511
    const int row0 = blockIdx.x * 16;               // 16 rows per block

    float acc[16];
    #pragma unroll
    for (int r = 0; r < 16; ++r) acc[r] = 0.f;

    for (int k = 0; k < D_MODEL; k += 4) {          // one panel: k = 0..511
        const float w0 = W[(size_t)(k + 0) * D_MODEL + col];
        const float w1 = W[(size_t)(k + 1) * D_MODEL + col];
        const float w2 = W[(size_t)(k + 2) * D_MODEL + col];
        const float w3 = W[(size_t)(k + 3) * D_MODEL + col];
        #pragma unroll
        for (int r = 0; r < 16; ++r) {
            const float4 xv = *reinterpret_cast<const float4*>(
                &x[(size_t)(row0 + r) * D_MODEL + k]);
            acc[r] = __fmaf_rn(xv.x, w0, acc[r]);
            acc[r] = __fmaf_rn(xv.y, w1, acc[r]);
            acc[r] = __fmaf_rn(xv.z, w2, acc[r]);
            acc[r] = __fmaf_rn(xv.w, w3, acc[r]);
        }
    }

    const float bc = bias[col];
    const int h = col >> 6, d = col & 63;
    #pragma unroll
    for (int r = 0; r < 16; ++r) {
        const int row = row0 + r;
        const int b = row >> 11, l = row & (L_SEQ - 1);
        Out[((size_t)((b * NHEAD + h) * L_SEQ + l)) * DH + d] =
            __fadd_rn(acc[r], bc);
    }
}

// ---- attention: BLAS-chain scores (LOCKED bits) -> exact fp32 top-38 ----
// Perf deltas vs round 14 (arithmetic bit-identical):
//  * 2 queries per wave (16/block, 4096 blocks): each K ds_read_b128 now
//    feeds 2 FMA chains -> per-query LDS-port traffic HALVED (r14 counter
//    math: LDS port was ~68% of kernel time with 8x cross-wave redundancy)
//  * double-buffered K tile + T14 async staging: global loads for tile t+1
//    issued before compute of t (hidden under ~6K cycles of FMA); ONE
//    barrier per tile (was 2)
//  * only 4 float4 staged in regs (r12's spill was 8 float4 + s[2][32]);
//    live set ~112 under the (512,2) 128-VGPR cap
__global__ __launch_bounds__(512, 2)
void attn_kernel(const float* __restrict__ Q, const float* __restrict__ K,
                 const float* __restrict__ V, float* __restrict__ ctx)
{
    __shared__ float Qs[QPB][DH];          // 4 KB
    __shared__ float Ks[2 * TILE_DW];      // 64 KB dbuf, elem = r*64 + (col^((r&7)<<2))
    __shared__ int   kidx[QPB][64];        // 4 KB  kept keys (ascending)
    __shared__ float kwgt[QPB][64];        // 4 KB  kept exp-weights

    // XCD swizzle: all 128 q-tiles of a (b,h) on one XCD (K/V L2-resident)
    const int bid = blockIdx.x;            // 0..4095
    const int xcd = bid & 7, jrem = bid >> 3;   // jrem 0..511
    const int bh  = xcd * 4 + (jrem >> 7);  // 0..31
    const int qt  = jrem & 127;             // 0..127
    const int b   = bh >> 3, h = bh & 7;

    const float* __restrict__ Qbh = Q + (size_t)bh * L_SEQ * DH;
    const float* __restrict__ Kbh = K + (size_t)bh * L_SEQ * DH;
    const float* __restrict__ Vbh = V + (size_t)bh * L_SEQ * DH;

    const int tid = threadIdx.x;
    const int wave = tid >> 6, lane = tid & 63;
    const int q0 = wave * 2;               // 2 queries per wave

    {   // stage Q tile (16x64): float2 per thread, coalesced
        const int q = tid >> 5, d0 = (tid & 31) << 1;
        *reinterpret_cast<float2*>(&Qs[q][d0]) =
            *reinterpret_cast<const float2*>(&Qbh[(size_t)(qt * QPB + q) * DH + d0]);
    }

    // swizzled LDS write indices (4 chunks x 512 threads x float4 = tile)
    const int fb = tid << 2;
    int sidx[4];
    #pragma unroll
    for (int c = 0; c < 4; ++c) {
        const int f = c * 2048 + fb;
        const int r = f >> 6, col = f & 63;
        sidx[c] = (r << 6) + (col ^ ((r & 7) << 2));
    }

    // prologue: load tile 0 into registers
    float4 stg0 = *reinterpret_cast<const float4*>(&Kbh[fb]);
    float4 stg1 = *reinterpret_cast<const float4*>(&Kbh[2048 + fb]);
    float4 stg2 = *reinterpret_cast<const float4*>(&Kbh[4096 + fb]);
    float4 stg3 = *reinterpret_cast<const float4*>(&Kbh[6144 + fb]);

    float s[2][32];

    #pragma unroll
    for (int t = 0; t < L_SEQ / KT; ++t) {        // 16 tiles, fully unrolled
        float* buf = &Ks[(t & 1) * TILE_DW];
        // write staged tile t into buf (ds_write_b128, 2-way banks = free)
        *reinterpret_cast<float4*>(&buf[sidx[0]]) = stg0;
        *reinterpret_cast<float4*>(&buf[sidx[1]]) = stg1;
        *reinterpret_cast<float4*>(&buf[sidx[2]]) = stg2;
        *reinterpret_cast<float4*>(&buf[sidx[3]]) = stg3;
        __syncthreads();                           // buf ready for all waves

        if (t < L_SEQ / KT - 1) {                  // issue t+1 loads early:
            const float* src = Kbh + (size_t)(t + 1) * TILE_DW;   // hidden
            stg0 = *reinterpret_cast<const float4*>(&src[fb]);     // under
            stg1 = *reinterpret_cast<const float4*>(&src[2048 + fb]); // FMA
            stg2 = *reinterpret_cast<const float4*>(&src[4096 + fb]);
            stg3 = *reinterpret_cast<const float4*>(&src[6144 + fb]);
        }

        // single FMA chain over d ascending per (q,key) — LOCKED order
        float v00 = 0.f, v01 = 0.f, v10 = 0.f, v11 = 0.f;
        #pragma unroll
        for (int dc = 0; dc < 16; ++dc) {
            const int sw = (dc ^ (lane & 7)) << 2;   // logical cols 4dc..4dc+3
            const float4 k0 = *reinterpret_cast<const float4*>(
                &buf[(lane << 6) + sw]);
            const float4 k1 = *reinterpret_cast<const float4*>(
                &buf[((64 + lane) << 6) + sw]);
            const float4 p0 = *reinterpret_cast<const float4*>(&Qs[q0][dc << 2]);
            const float4 p1 = *reinterpret_cast<const float4*>(&Qs[q0 + 1][dc << 2]);
            v00 = __fmaf_rn(p0.x, k0.x, v00);
            v00 = __fmaf_rn(p0.y, k0.y, v00);
            v00 = __fmaf_rn(p0.z, k0.z, v00);
            v00 = __fmaf_rn(p0.w, k0.w, v00);
            v01 = __fmaf_rn(p0.x, k1.x, v01);
            v01 = __fmaf_rn(p0.y, k1.y, v01);
            v01 = __fmaf_rn(p0.z, k1.z, v01);
            v01 = __fmaf_rn(p0.w, k1.w, v01);
            v10 = __fmaf_rn(p1.x, k0.x, v10);
            v10 = __fmaf_rn(p1.y, k0.y, v10);
            v10 = __fmaf_rn(p1.z, k0.z, v10);
            v10 = __fmaf_rn(p1.w, k0.w, v10);
            v11 = __fmaf_rn(p1.x, k1.x, v11);
            v11 = __fmaf_rn(p1.y, k1.y, v11);
            v11 = __fmaf_rn(p1.z, k1.z, v11);
            v11 = __fmaf_rn(p1.w, k1.w, v11);
        }
        // /sqrt(64) = *0.125, exact
        s[0][2*t]     = __fmul_rn(v00, 0.125f);
        s[0][2*t + 1] = __fmul_rn(v01, 0.125f);
        s[1][2*t]     = __fmul_rn(v10, 0.125f);
        s[1][2*t + 1] = __fmul_rn(v11, 0.125f);
        // no second barrier: next tile writes buf^1 (not read this tile);
        // buf is overwritten only at t+2, after the t+1 barrier
    }

    #pragma unroll
    for (int q = 0; q < 2; ++q) {
        const int qg = q0 + q;

        // map scores to monotone uint space (in place)
        #pragma unroll
        for (int j = 0; j < 32; ++j)
            s[q][j] = __uint_as_float(mapmono(s[q][j]));

        // exact fp32 38th-largest: binary search in mapped-uint space.
        // count via ballot+popc -> v_cmp + scalar s_bcnt1 (SALU pipe)
        unsigned long long lo = 0ull, hi = 0x100000000ull;
        while (hi - lo > 1ull) {
            const unsigned mid = (unsigned)((lo + hi) >> 1);
            int cnt = 0;
            #pragma unroll
            for (int j = 0; j < 32; ++j)
                cnt += (int)__popcll(__ballot(__float_as_uint(s[q][j]) >= mid));
            if (cnt >= U_TOP) lo = mid; else hi = mid;
        }
        const unsigned thrU = (unsigned)lo;     // mapped bits of the 38th value

        // row max in mapped space (top-1 always kept)
        unsigned um = 0u;
        #pragma unroll
        for (int j = 0; j < 32; ++j) {
            const unsigned ub = __float_as_uint(s[q][j]);
            um = um > ub ? um : ub;
        }
        #pragma unroll
        for (int off = 32; off; off >>= 1) {
            const unsigned o = (unsigned)__shfl_xor((int)um, off);
            um = um > o ? um : o;
        }
        const float mrow = __uint_as_float((um & 0x80000000u) ? (um & 0x7FFFFFFFu) : ~um);

        // compact kept keys (ascending key order) via ballot prefix-sum
        int base = 0; float lsum = 0.f;
        #pragma unroll
        for (int j = 0; j < 32; ++j) {
            const unsigned ub = __float_as_uint(s[q][j]);
            const bool keep = (ub >= thrU);     // == !(score < thr), np semantics
            const unsigned long long mk = __ballot(keep);
            if (keep) {
                const float sc = __uint_as_float((ub & 0x80000000u) ? (ub & 0x7FFFFFFFu) : ~ub);
                const float w = __expf(sc - mrow);
                const int pos = base + (int)__popcll(mk & ((1ull << lane) - 1ull));
                if (pos < 64) {
                    kidx[qg][pos] = ((j >> 1) << 7) + ((j & 1) << 6) + lane;
                    kwgt[qg][pos] = w;
                }
                lsum += w;
            }
            base += (int)__popcll(mk);
        }
        #pragma unroll
        for (int off = 32; off; off >>= 1) lsum += __shfl_xor(lsum, off);
        const int nk = base < 64 ? base : 64;

        // ctx[d] = (sum over kept, ascending key order) w * V[k][d] / Z
        // 8-deep load pipeline; FMA chain order preserved (ascending i)
        float acc = 0.f;
        int i = 0;
        for (; i + 8 <= nk; i += 8) {
            float wv[8], vv[8];
            #pragma unroll
            for (int u = 0; u < 8; ++u) {
                wv[u] = kwgt[qg][i + u];
                vv[u] = Vbh[(size_t)kidx[qg][i + u] * DH + lane];
            }
            #pragma unroll
            for (int u = 0; u < 8; ++u)
                acc = __fmaf_rn(wv[u], vv[u], acc);
        }
        for (; i < nk; ++i)
            acc = __fmaf_rn(kwgt[qg][i], Vbh[(size_t)kidx[qg][i] * DH + lane], acc);
        acc /= lsum;

        const int l = qt * QPB + qg;
        ctx[((size_t)(b * L_SEQ + l)) * D_MODEL + h * DH + lane] = acc;
    }
}

extern "C" void kernel_launch(void* const* d_in, const int* in_sizes, int n_in,
                              void* d_out, int out_size, void* d_ws, size_t ws_size,
                              hipStream_t stream) {
    (void)in_sizes; (void)n_in; (void)out_size; (void)ws_size;
    const float* x  = (const float*)d_in[0];
    const float* Wq = (const float*)d_in[1];
    const float* bq = (const float*)d_in[2];
    const float* Wk = (const float*)d_in[3];
    const float* bk = (const float*)d_in[4];
    const float* Wv = (const float*)d_in[5];
    const float* bv = (const float*)d_in[6];
    const float* Wo = (const float*)d_in[7];
    const float* bo = (const float*)d_in[8];
    float* out = (float*)d_out;

    // ws: Qf | Kf | V | ctx = 4 x 16.78 MB = 67.1 MB
    const size_t NE = (size_t)B_SZ * NHEAD * L_SEQ * DH;   // 4.19e6
    float* Qf = (float*)d_ws;
    float* Kf = Qf + NE;
    float* Vw = Kf + NE;
    float* Cw = Vw + NE;

    const dim3 gq(512, 2), g(128, 8), blk(256);
    chain_gemm_qk<<<gq, blk, 0, stream>>>(x, Wq, bq, Qf);
    chain_gemm_qk<<<gq, blk, 0, stream>>>(x, Wk, bk, Kf);
    gemm512<1>   <<<g,  blk, 0, stream>>>(x, Wv, bv, Vw);
    attn_kernel  <<<dim3(4096), dim3(512), 0, stream>>>(Qf, Kf, Vw, Cw);
    gemm512<0>   <<<g,  blk, 0, stream>>>(Cw, Wo, bo, out);
}

// Round 17
// 1374.721 us; speedup vs baseline: 1.2888x; 1.2888x over previous
//
#include <hip/hip_runtime.h>
#include <cstdint>
#include <cstddef>

#define D_MODEL 512
#define NHEAD   8
#define DH      64
#define B_SZ    4
#define L_SEQ   2048
#define U_TOP   38          // int(5*ln(2048)) = 38
#define QPB     8           // queries per block (2 per wave, 4 waves)
#define KT      128         // key tile staged in LDS

// monotone float<->uint mapping (order-preserving, exact)
__device__ __forceinline__ unsigned mapmono(float f) {
    unsigned u = __float_as_uint(f);
    return (u & 0x80000000u) ? ~u : (u | 0x80000000u);
}

// ---------------- fp32 GEMM: C(8192x512) = A @ W + b ----------------
// Accurate tiled version for V and the output projection (order-insensitive).
// MODE 0: C row-major (b,l,dm)   MODE 1: scatter to (b,h,l,d)
template<int MODE>
__global__ __launch_bounds__(256)
void gemm512(const float* __restrict__ A, const float* __restrict__ W,
             const float* __restrict__ bias, float* __restrict__ C)
{
    __shared__ float As[16][68];
    __shared__ float Bs[16][68];
    const int tid  = threadIdx.x;
    const int row0 = blockIdx.x * 64;
    const int col0 = blockIdx.y * 64;
    const int ty = tid >> 4, tx = tid & 15;
    float acc[4][4] = {};

    for (int kt = 0; kt < D_MODEL; kt += 16) {
        {
            const int m = tid >> 2, k = (tid & 3) << 2;
            const float4 a = *reinterpret_cast<const float4*>(
                &A[(size_t)(row0 + m) * D_MODEL + kt + k]);
            As[k + 0][m] = a.x; As[k + 1][m] = a.y;
            As[k + 2][m] = a.z; As[k + 3][m] = a.w;
        }
        {
            const int k = tid >> 4, n = (tid & 15) << 2;
            *reinterpret_cast<float4*>(&Bs[k][n]) =
                *reinterpret_cast<const float4*>(
                    &W[(size_t)(kt + k) * D_MODEL + col0 + n]);
        }
        __syncthreads();
        #pragma unroll
        for (int kk = 0; kk < 16; ++kk) {
            const float4 a4 = *reinterpret_cast<const float4*>(&As[kk][ty << 2]);
            const float4 b4 = *reinterpret_cast<const float4*>(&Bs[kk][tx << 2]);
            const float av[4] = {a4.x, a4.y, a4.z, a4.w};
            const float bv[4] = {b4.x, b4.y, b4.z, b4.w};
            #pragma unroll
            for (int i = 0; i < 4; ++i)
                #pragma unroll
                for (int j = 0; j < 4; ++j)
                    acc[i][j] += av[i] * bv[j];
        }
        __syncthreads();
    }

    #pragma unroll
    for (int i = 0; i < 4; ++i) {
        const int r = row0 + (ty << 2) + i;
        const int cb = col0 + (tx << 2);
        float4 v;
        v.x = acc[i][0] + bias[cb + 0];
        v.y = acc[i][1] + bias[cb + 1];
        v.z = acc[i][2] + bias[cb + 2];
        v.w = acc[i][3] + bias[cb + 3];
        if (MODE == 0) {
            *reinterpret_cast<float4*>(&C[(size_t)r * D_MODEL + cb]) = v;
        } else {
            const int b = r >> 11, l = r & (L_SEQ - 1);
            const int h = cb >> 6, d = cb & 63;
            *reinterpret_cast<float4*>(
                &C[(size_t)((b * NHEAD + h) * L_SEQ + l) * DH + d]) = v;
        }
    }
}

// ----- np-replica GEMM for Q,K: SINGLE K-panel sequential FMA chain -----
// (LOCKED arithmetic — passed round 9. Per C element: ONE fp32 accumulator,
// FMA over k=0..511 ascending, then one fp32 bias add.)
__global__ __launch_bounds__(256)
void chain_gemm_qk(const float* __restrict__ x, const float* __restrict__ W,
                   const float* __restrict__ bias, float* __restrict__ Out)
{
    const int tid  = threadIdx.x;
    const int col  = blockIdx.y * 256 + tid;        // 0..511
    const int row0 = blockIdx.x * 16;               // 16 rows per block

    float acc[16];
    #pragma unroll
    for (int r = 0; r < 16; ++r) acc[r] = 0.f;

    for (int k = 0; k < D_MODEL; k += 4) {          // one panel: k = 0..511
        const float w0 = W[(size_t)(k + 0) * D_MODEL + col];
        const float w1 = W[(size_t)(k + 1) * D_MODEL + col];
        const float w2 = W[(size_t)(k + 2) * D_MODEL + col];
        const float w3 = W[(size_t)(k + 3) * D_MODEL + col];
        #pragma unroll
        for (int r = 0; r < 16; ++r) {
            const float4 xv = *reinterpret_cast<const float4*>(
                &x[(size_t)(row0 + r) * D_MODEL + k]);
            acc[r] = __fmaf_rn(xv.x, w0, acc[r]);
            acc[r] = __fmaf_rn(xv.y, w1, acc[r]);
            acc[r] = __fmaf_rn(xv.z, w2, acc[r]);
            acc[r] = __fmaf_rn(xv.w, w3, acc[r]);
        }
    }

    const float bc = bias[col];
    const int h = col >> 6, d = col & 63;
    #pragma unroll
    for (int r = 0; r < 16; ++r) {
        const int row = row0 + r;
        const int b = row >> 11, l = row & (L_SEQ - 1);
        Out[((size_t)((b * NHEAD + h) * L_SEQ + l)) * DH + d] =
            __fadd_rn(acc[r], bc);
    }
}

// ---- attention: BLAS-chain scores (LOCKED bits) -> exact fp32 top-38 ----
// Perf deltas vs r14/r16 (arithmetic bit-identical):
//  * 2 queries per wave BUT only q0's scores in registers (s[32], r14's
//    proven 64-VGPR pressure); q1's scores stream to an LDS spill slab
//    (2 ds_write_b32/tile, bank-clean [j*64+lane]) and reload after q0's
//    selection frees the score registers. Kills the s[2][32]=64-reg
//    burden that spilled r10/r12/r16 (WRITE_SIZE canary 1-5 GB).
//  * each K ds_read_b128 feeds 2 queries -> per-CU LDS-port time ~halved
//    (r14 was LDS-port-bound: 512 b128/query x 12cyc x 256 q/CU ~ 655us)
//  * staging via PRE-SWIZZLED global source + linear LDS write (no sidx
//    regs, no held staging): Ks slot s holds K[s>>6][(s&63)^(((s>>6)&7)<<2)]
__global__ __launch_bounds__(256, 2)
void attn_kernel(const float* __restrict__ Q, const float* __restrict__ K,
                 const float* __restrict__ V, float* __restrict__ ctx)
{
    __shared__ float Qs[QPB][DH];          // 2 KB
    __shared__ float Ks[KT * DH];          // 32 KB swizzled store
    __shared__ float sspill[4][L_SEQ];     // 32 KB q1 scores: [wave][j*64+lane]
    __shared__ int   kidx[QPB][64];        // 2 KB  kept keys (ascending)
    __shared__ float kwgt[QPB][64];        // 2 KB  kept exp-weights
                                           // total ~70 KB -> 2 blocks/CU

    // XCD swizzle: all 256 q-tiles of a (b,h) on one XCD (K/V L2-resident)
    const int bid = blockIdx.x;            // 0..8191
    const int xcd = bid & 7, jrem = bid >> 3;
    const int bh  = xcd * 4 + (jrem >> 8); // 0..31
    const int qt  = jrem & 255;            // 0..255
    const int b   = bh >> 3, h = bh & 7;

    const float* __restrict__ Qbh = Q + (size_t)bh * L_SEQ * DH;
    const float* __restrict__ Kbh = K + (size_t)bh * L_SEQ * DH;
    const float* __restrict__ Vbh = V + (size_t)bh * L_SEQ * DH;

    const int tid = threadIdx.x;
    const int wave = tid >> 6, lane = tid & 63;
    const int q0 = wave * 2;               // 2 queries per wave

    {   // stage Q tile (8x64): float2 per thread, coalesced
        const int q = tid >> 5, d0 = (tid & 31) << 1;
        *reinterpret_cast<float2*>(&Qs[q][d0]) =
            *reinterpret_cast<const float2*>(&Qbh[(size_t)(qt * QPB + q) * DH + d0]);
    }

    // pre-swizzled global source offsets (tile-invariant, 8 chunks)
    int soff[8];
    #pragma unroll
    for (int c = 0; c < 8; ++c) {
        const int slot = c * 1024 + tid * 4;
        const int r = slot >> 6, cp = slot & 63;
        soff[c] = (r << 6) + (cp ^ ((r & 7) << 2));
    }

    float s[32];                            // q0 scores (q1 -> sspill)

    #pragma unroll
    for (int t = 0; t < L_SEQ / KT; ++t) {        // 16 tiles, fully unrolled
        __syncthreads();                           // Ks safe to overwrite
        const float* src = Kbh + (size_t)t * (KT * DH);
        #pragma unroll
        for (int c = 0; c < 8; ++c)               // linear write, swz source
            *reinterpret_cast<float4*>(&Ks[c * 1024 + tid * 4]) =
                *reinterpret_cast<const float4*>(&src[soff[c]]);
        __syncthreads();

        // single FMA chain over d ascending per (q,key) — LOCKED order
        float v00 = 0.f, v01 = 0.f, v10 = 0.f, v11 = 0.f;
        #pragma unroll
        for (int dc = 0; dc < 16; ++dc) {
            const int sw = (dc ^ (lane & 7)) << 2;   // logical cols 4dc..4dc+3
            const float4 k0 = *reinterpret_cast<const float4*>(
                &Ks[(lane << 6) + sw]);
            const float4 k1 = *reinterpret_cast<const float4*>(
                &Ks[((64 + lane) << 6) + sw]);
            const float4 p0 = *reinterpret_cast<const float4*>(&Qs[q0][dc << 2]);
            const float4 p1 = *reinterpret_cast<const float4*>(&Qs[q0 + 1][dc << 2]);
            v00 = __fmaf_rn(p0.x, k0.x, v00);
            v00 = __fmaf_rn(p0.y, k0.y, v00);
            v00 = __fmaf_rn(p0.z, k0.z, v00);
            v00 = __fmaf_rn(p0.w, k0.w, v00);
            v01 = __fmaf_rn(p0.x, k1.x, v01);
            v01 = __fmaf_rn(p0.y, k1.y, v01);
            v01 = __fmaf_rn(p0.z, k1.z, v01);
            v01 = __fmaf_rn(p0.w, k1.w, v01);
            v10 = __fmaf_rn(p1.x, k0.x, v10);
            v10 = __fmaf_rn(p1.y, k0.y, v10);
            v10 = __fmaf_rn(p1.z, k0.z, v10);
            v10 = __fmaf_rn(p1.w, k0.w, v10);
            v11 = __fmaf_rn(p1.x, k1.x, v11);
            v11 = __fmaf_rn(p1.y, k1.y, v11);
            v11 = __fmaf_rn(p1.z, k1.z, v11);
            v11 = __fmaf_rn(p1.w, k1.w, v11);
        }
        // /sqrt(64) = *0.125, exact; q0 -> regs, q1 -> LDS spill (bit-copy)
        s[2*t]     = __fmul_rn(v00, 0.125f);
        s[2*t + 1] = __fmul_rn(v01, 0.125f);
        sspill[wave][(2*t) * 64 + lane]     = __fmul_rn(v10, 0.125f);
        sspill[wave][(2*t + 1) * 64 + lane] = __fmul_rn(v11, 0.125f);
    }

    #pragma unroll
    for (int qq = 0; qq < 2; ++qq) {
        if (qq) {   // q0 done, its score regs dead -> reload q1 (same-wave RAW)
            #pragma unroll
            for (int j = 0; j < 32; ++j)
                s[j] = sspill[wave][j * 64 + lane];
        }
        const int qg = q0 + qq;

        // map scores to monotone uint space (in place)
        #pragma unroll
        for (int j = 0; j < 32; ++j)
            s[j] = __uint_as_float(mapmono(s[j]));

        // exact fp32 38th-largest: binary search in mapped-uint space.
        // count via ballot+popc -> v_cmp + scalar s_bcnt1 (SALU pipe)
        unsigned long long lo = 0ull, hi = 0x100000000ull;
        while (hi - lo > 1ull) {
            const unsigned mid = (unsigned)((lo + hi) >> 1);
            int cnt = 0;
            #pragma unroll
            for (int j = 0; j < 32; ++j)
                cnt += (int)__popcll(__ballot(__float_as_uint(s[j]) >= mid));
            if (cnt >= U_TOP) lo = mid; else hi = mid;
        }
        const unsigned thrU = (unsigned)lo;     // mapped bits of the 38th value

        // row max in mapped space (top-1 always kept)
        unsigned um = 0u;
        #pragma unroll
        for (int j = 0; j < 32; ++j) {
            const unsigned ub = __float_as_uint(s[j]);
            um = um > ub ? um : ub;
        }
        #pragma unroll
        for (int off = 32; off; off >>= 1) {
            const unsigned o = (unsigned)__shfl_xor((int)um, off);
            um = um > o ? um : o;
        }
        const float mrow = __uint_as_float((um & 0x80000000u) ? (um & 0x7FFFFFFFu) : ~um);

        // compact kept keys (ascending key order) via ballot prefix-sum
        int base = 0; float lsum = 0.f;
        #pragma unroll
        for (int j = 0; j < 32; ++j) {
            const unsigned ub = __float_as_uint(s[j]);
            const bool keep = (ub >= thrU);     // == !(score < thr), np semantics
            const unsigned long long mk = __ballot(keep);
            if (keep) {
                const float sc = __uint_as_float((ub & 0x80000000u) ? (ub & 0x7FFFFFFFu) : ~ub);
                const float w = __expf(sc - mrow);
                const int pos = base + (int)__popcll(mk & ((1ull << lane) - 1ull));
                if (pos < 64) {
                    kidx[qg][pos] = ((j >> 1) << 7) + ((j & 1) << 6) + lane;
                    kwgt[qg][pos] = w;
                }
                lsum += w;
            }
            base += (int)__popcll(mk);
        }
        #pragma unroll
        for (int off = 32; off; off >>= 1) lsum += __shfl_xor(lsum, off);
        const int nk = base < 64 ? base : 64;

        // ctx[d] = (sum over kept, ascending key order) w * V[k][d] / Z
        // 8-deep load pipeline; FMA chain order preserved (ascending i)
        float acc = 0.f;
        int i = 0;
        for (; i + 8 <= nk; i += 8) {
            float wv[8], vv[8];
            #pragma unroll
            for (int u = 0; u < 8; ++u) {
                wv[u] = kwgt[qg][i + u];
                vv[u] = Vbh[(size_t)kidx[qg][i + u] * DH + lane];
            }
            #pragma unroll
            for (int u = 0; u < 8; ++u)
                acc = __fmaf_rn(wv[u], vv[u], acc);
        }
        for (; i < nk; ++i)
            acc = __fmaf_rn(kwgt[qg][i], Vbh[(size_t)kidx[qg][i] * DH + lane], acc);
        acc /= lsum;

        const int l = qt * QPB + qg;
        ctx[((size_t)(b * L_SEQ + l)) * D_MODEL + h * DH + lane] = acc;
    }
}

extern "C" void kernel_launch(void* const* d_in, const int* in_sizes, int n_in,
                              void* d_out, int out_size, void* d_ws, size_t ws_size,
                              hipStream_t stream) {
    (void)in_sizes; (void)n_in; (void)out_size; (void)ws_size;
    const float* x  = (const float*)d_in[0];
    const float* Wq = (const float*)d_in[1];
    const float* bq = (const float*)d_in[2];
    const float* Wk = (const float*)d_in[3];
    const float* bk = (const float*)d_in[4];
    const float* Wv = (const float*)d_in[5];
    const float* bv = (const float*)d_in[6];
    const float* Wo = (const float*)d_in[7];
    const float* bo = (const float*)d_in[8];
    float* out = (float*)d_out;

    // ws: Qf | Kf | V | ctx = 4 x 16.78 MB = 67.1 MB
    const size_t NE = (size_t)B_SZ * NHEAD * L_SEQ * DH;   // 4.19e6
    float* Qf = (float*)d_ws;
    float* Kf = Qf + NE;
    float* Vw = Kf + NE;
    float* Cw = Vw + NE;

    const dim3 gq(512, 2), g(128, 8), blk(256);
    chain_gemm_qk<<<gq, blk, 0, stream>>>(x, Wq, bq, Qf);
    chain_gemm_qk<<<gq, blk, 0, stream>>>(x, Wk, bk, Kf);
    gemm512<1>   <<<g,  blk, 0, stream>>>(x, Wv, bv, Vw);
    attn_kernel  <<<dim3(8192), blk, 0, stream>>>(Qf, Kf, Vw, Cw);
    gemm512<0>   <<<g,  blk, 0, stream>>>(Cw, Wo, bo, out);
}